// Round 14
// baseline (388.101 us; speedup 1.0000x reference)
//
#include <hip/hip_runtime.h>
#include <cstdint>

// Problem constants (B,S,D,H) from the reference
#define B_ 64
#define S_ 2048
#define D_ 512
#define H_ 512

using f32x4  = __attribute__((ext_vector_type(4))) float;
using bf16x8 = __attribute__((ext_vector_type(8))) short;
using u32x2  = __attribute__((ext_vector_type(2))) unsigned int;

__device__ __forceinline__ unsigned short f2bf(float f) {
  unsigned u = __float_as_uint(f);
  u += 0x7FFFu + ((u >> 16) & 1u);   // round-to-nearest-even
  return (unsigned short)(u >> 16);
}
// packed f32x2 -> bf16x2 (RTE), hardware op
__device__ __forceinline__ unsigned int cvtpk(float lo, float hi) {
  unsigned int r;
  asm("v_cvt_pk_bf16_f32 %0, %1, %2" : "=v"(r) : "v"(lo), "v"(hi));
  return r;
}
// tanh via v_exp_f32: 1 - 2/(exp2(2x*log2e)+1); exact saturation at +-inf
__device__ __forceinline__ float fast_tanh(float x) {
  float t = __builtin_amdgcn_exp2f(x * 2.8853900817779268f);
  return 1.0f - 2.0f * __builtin_amdgcn_rcpf(t + 1.0f);
}

__device__ __forceinline__ void barrier_raw() {
  asm volatile("" ::: "memory");
  __builtin_amdgcn_s_barrier();
  asm volatile("" ::: "memory");
}

// ---------------------------------------------------------------------------
// k_prep: blocks [0,128): di[b,h] = hidden[b,:].Wd[h,:] + bd[h]
//         blocks [128,256): We fp32 -> bf16 (32768 chunks of 8)
__global__ void k_prep(const float* __restrict__ hidden, const float* __restrict__ Wd,
                       const float* __restrict__ bd, float* __restrict__ di,
                       const float* __restrict__ We, unsigned short* __restrict__ Web) {
  if (blockIdx.x < 128) {
    int idx = blockIdx.x * 256 + threadIdx.x;   // 32768 total
    int h = idx >> 6;
    int b = idx & 63;
    const f32x4* hp = (const f32x4*)(hidden + (size_t)b * D_);
    const f32x4* wp = (const f32x4*)(Wd + (size_t)h * D_);
    float acc = 0.f;
#pragma unroll 8
    for (int i = 0; i < D_ / 4; ++i) {
      f32x4 x = hp[i], y = wp[i];
      acc += x[0] * y[0] + x[1] * y[1] + x[2] * y[2] + x[3] * y[3];
    }
    di[b * H_ + h] = acc + bd[h];
  } else {
    int i = (blockIdx.x - 128) * 256 + threadIdx.x;   // 32768 chunks
    const f32x4* p = (const f32x4*)(We + (size_t)i * 8);
    f32x4 a = p[0], b = p[1];
    bf16x8 o;
    o[0] = (short)f2bf(a[0]); o[1] = (short)f2bf(a[1]);
    o[2] = (short)f2bf(a[2]); o[3] = (short)f2bf(a[3]);
    o[4] = (short)f2bf(b[0]); o[5] = (short)f2bf(b[1]);
    o[6] = (short)f2bf(b[2]); o[7] = (short)f2bf(b[3]);
    *(bf16x8*)(Web + (size_t)i * 8) = o;
  }
}

// ---------------------------------------------------------------------------
// ei-GEMM, fp32 A read directly; reg-staged A with in-register cvt_pk, fused
// ui partials. Tile 128x128, 4 waves (2x2), BK=32, 16 k-steps, 33KB LDS.
// THREE named register sets (a/b/c): tile T lives in set T%3. At iter kt:
//   lgkmcnt(0); barrier                  // buf[kt&1] visible block-wide
//   ds_read frags(buf[kt&1])
//   LOADN(set[kt%3], kt+3)               // 2-ITERATION slack to its WRITEN
//   setprio(1); 16 MFMA; setprio(0)
//   WRITEN(set[(kt+1)%3], buf^1)         // tile kt+1, loaded 2 iters ago
// R9 proved this schedule correct (passed) but spilled at launch_bounds(256,4)
// (unified VGPR+AGPR cap 128 < 156 needed). At (256,3) the cap is 170:
// 3 sets x 24 + 64 AGPR acc + addressing ~ 156 fits -> no spill, and the
// 2-iter slack (~800-1000 cyc) covers the ~900-cyc HBM latency that R8's
// ablation identified as the +100us cost of the global-load path.
__global__ __launch_bounds__(256, 3) void k_ei_gemm(
    const float* __restrict__ A, const unsigned short* __restrict__ Bw,
    const float* __restrict__ be, const float* __restrict__ V,
    const float* __restrict__ di, float* __restrict__ ui4) {
  __shared__ __align__(16) unsigned short ldsA[2][128 * 32];   // 8KB each
  __shared__ __align__(16) unsigned short ldsB[2][128 * 32];
  __shared__ float ured[4][64];

  const int bid = blockIdx.x;
  const int swz = (bid & 7) * 512 + (bid >> 3);   // bijective XCD chunking (4096%8==0)
  const int row0 = (swz >> 2) << 7;               // 1024 m-tiles of 128 rows
  const int nt   = swz & 3;
  const int col0 = nt << 7;

  const int t  = threadIdx.x;
  const int l  = t & 63;
  const int w  = t >> 6;          // 4 waves, 2M x 2N
  const int wm = (w >> 1) << 6;
  const int wn = (w & 1) << 6;
  const int lr = l & 15;
  const int lg = l >> 4;

  // staging maps (A fp32 rows of 128B; B bf16 rows of 64B)
  const float* gA = A + (size_t)(row0 + w * 32 + (l >> 3)) * D_ + ((l & 7) << 2);
  const unsigned short* gB = Bw + (size_t)(col0 + w * 32 + (l >> 2)) * D_ + ((l & 3) << 3);

  // LDS write slots (16B granules, phys = logical ^ ((row>>1)&3))
  const int sA = (((l & 7) >> 1) ^ ((l >> 4) & 3));
  const int eA0 = (w * 32 + (l >> 3)) * 32 + sA * 8 + (l & 1) * 4;
  const int sB = ((l & 3) ^ ((l >> 3) & 3));
  const int eB0 = (w * 32 + (l >> 2)) * 32 + sB * 8;
  const int rs = (lg ^ ((lr >> 1) & 3)) << 3;

  // three named staging register sets (rule #20: never runtime-index)
  f32x4  rA0a, rA1a, rA2a, rA3a;  bf16x8 rB0a, rB1a;
  f32x4  rA0b, rA1b, rA2b, rA3b;  bf16x8 rB0b, rB1b;
  f32x4  rA0c, rA1c, rA2c, rA3c;  bf16x8 rB0c, rB1c;

#define LOADN(S, kk) do {                               \
    const float* a_ = gA + ((kk) << 5);                 \
    rA0##S = *(const f32x4*)(a_);                       \
    rA1##S = *(const f32x4*)(a_ + 8 * D_);              \
    rA2##S = *(const f32x4*)(a_ + 16 * D_);             \
    rA3##S = *(const f32x4*)(a_ + 24 * D_);             \
    const unsigned short* b_ = gB + ((kk) << 5);        \
    rB0##S = *(const bf16x8*)(b_);                      \
    rB1##S = *(const bf16x8*)(b_ + 16 * D_);            \
  } while (0)

#define WRITEN(S, bf) do {                                                  \
    u32x2 p0 = {cvtpk(rA0##S[0], rA0##S[1]), cvtpk(rA0##S[2], rA0##S[3])};  \
    u32x2 p1 = {cvtpk(rA1##S[0], rA1##S[1]), cvtpk(rA1##S[2], rA1##S[3])};  \
    u32x2 p2 = {cvtpk(rA2##S[0], rA2##S[1]), cvtpk(rA2##S[2], rA2##S[3])};  \
    u32x2 p3 = {cvtpk(rA3##S[0], rA3##S[1]), cvtpk(rA3##S[2], rA3##S[3])};  \
    *(u32x2*)&ldsA[bf][eA0]       = p0;                                     \
    *(u32x2*)&ldsA[bf][eA0 + 256] = p1;                                     \
    *(u32x2*)&ldsA[bf][eA0 + 512] = p2;                                     \
    *(u32x2*)&ldsA[bf][eA0 + 768] = p3;                                     \
    *(bf16x8*)&ldsB[bf][eB0]       = rB0##S;                                \
    *(bf16x8*)&ldsB[bf][eB0 + 512] = rB1##S;                                \
  } while (0)

  f32x4 acc[4][4];
  const f32x4 z = {0.f, 0.f, 0.f, 0.f};
#pragma unroll
  for (int mi = 0; mi < 4; ++mi)
#pragma unroll
    for (int ni = 0; ni < 4; ++ni) acc[mi][ni] = z;

#define KBODY(bf, LD, WR) do {                                              \
    asm volatile("s_waitcnt lgkmcnt(0)" ::: "memory");                      \
    barrier_raw();                                                          \
    bf16x8 af[4], bq[4];                                                    \
    _Pragma("unroll") for (int mi = 0; mi < 4; ++mi)                        \
      af[mi] = *(const bf16x8*)&ldsA[bf][(wm + mi * 16 + lr) * 32 + rs];    \
    _Pragma("unroll") for (int ni = 0; ni < 4; ++ni)                        \
      bq[ni] = *(const bf16x8*)&ldsB[bf][(wn + ni * 16 + lr) * 32 + rs];    \
    LD;                                                                     \
    __builtin_amdgcn_s_setprio(1);                                          \
    _Pragma("unroll") for (int mi = 0; mi < 4; ++mi)                        \
      _Pragma("unroll") for (int ni = 0; ni < 4; ++ni)                      \
        acc[mi][ni] = __builtin_amdgcn_mfma_f32_16x16x32_bf16(              \
            af[mi], bq[ni], acc[mi][ni], 0, 0, 0);                          \
    __builtin_amdgcn_s_setprio(0);                                          \
    WR;                                                                     \
  } while (0)

  // prologue: tiles 0,1,2 -> sets a,b,c; tile0 -> buf0
  LOADN(a, 0);
  LOADN(b, 1);
  LOADN(c, 2);
  WRITEN(a, 0);

  // steady state: period-6 pattern (buf mod 2, set mod 3), kt = 0..11
  for (int u = 0; u < 2; ++u) {
    const int kt = 6 * u;
    KBODY(0, LOADN(a, kt + 3), WRITEN(b, 1));   // kt+0
    KBODY(1, LOADN(b, kt + 4), WRITEN(c, 0));   // kt+1
    KBODY(0, LOADN(c, kt + 5), WRITEN(a, 1));   // kt+2
    KBODY(1, LOADN(a, kt + 6), WRITEN(b, 0));   // kt+3
    KBODY(0, LOADN(b, kt + 7), WRITEN(c, 1));   // kt+4
    KBODY(1, LOADN(c, kt + 8), WRITEN(a, 0));   // kt+5
  }
  // tail: kt = 12..15 (tile15 loaded at kt=12; no loads after)
  KBODY(0, LOADN(a, 15), WRITEN(b, 1));         // kt=12: write tile13
  KBODY(1, (void)0,      WRITEN(c, 0));         // kt=13: write tile14
  KBODY(0, (void)0,      WRITEN(a, 1));         // kt=14: write tile15
  KBODY(1, (void)0,      (void)0);              // kt=15
#undef KBODY
#undef LOADN
#undef WRITEN

  // fused ui partials over this block's 128 columns; atomic-free.
  // C/D layout: col = lr, row = lg*4 + j within each 16x16 frag.
  const int b = row0 >> 11;   // BM=128 divides S=2048 -> block-uniform batch
  float uacc[4][4];
#pragma unroll
  for (int mi = 0; mi < 4; ++mi)
#pragma unroll
    for (int j = 0; j < 4; ++j) uacc[mi][j] = 0.f;

#pragma unroll
  for (int ni = 0; ni < 4; ++ni) {
    const int gc = col0 + wn + ni * 16 + lr;
    const float vv = V[gc];
    const float base = di[b * H_ + gc] + be[gc];
#pragma unroll
    for (int mi = 0; mi < 4; ++mi)
#pragma unroll
      for (int j = 0; j < 4; ++j)
        uacc[mi][j] += vv * fast_tanh(base + acc[mi][ni][j]);
  }
#pragma unroll
  for (int mi = 0; mi < 4; ++mi)
#pragma unroll
    for (int j = 0; j < 4; ++j) {
      float s = uacc[mi][j];
      s += __shfl_xor(s, 1);
      s += __shfl_xor(s, 2);
      s += __shfl_xor(s, 4);
      s += __shfl_xor(s, 8);
      if (lr == 0) ured[w][mi * 16 + (lg << 2) + j] = s;
    }
  __syncthreads();
  if (t < 128) {
    const int r = t & 63, half = t >> 6;   // half 0: waves 0+1; 1: waves 2+3
    ui4[nt * (B_ * S_) + row0 + half * 64 + r] =
        ured[half * 2][r] + ured[half * 2 + 1][r];
  }
}

// ---------------------------------------------------------------------------
// softmax over S per batch row: sums the 4 ui partials, applies mask -> -inf.
__global__ void k_softmax(const float* __restrict__ ui4, const void* __restrict__ mask,
                          float* __restrict__ alpha) {
  __shared__ float red[4];
  __shared__ int sfl;
  const int b = blockIdx.x, t = threadIdx.x;
  const int l = t & 63, w = t >> 6;

  if (t == 0) sfl = 0;
  const unsigned int* mw = (const unsigned int*)mask;
  unsigned det = (mw[b * 512 + t] | mw[b * 512 + 256 + t]) & 0xFFFFFF00u;
  __syncthreads();
  if (det) atomicOr(&sfl, 1);
  __syncthreads();
  const int fl = sfl;   // 1 => byte layout

  float u[8];
#pragma unroll
  for (int i = 0; i < 8; ++i) {
    const int idx = b * S_ + t + i * 256;
    const int msk = fl ? (int)((const unsigned char*)mask)[idx]
                       : ((const int*)mask)[idx];
    const float uv = ui4[idx] + ui4[idx + B_ * S_] + ui4[idx + 2 * B_ * S_] +
                     ui4[idx + 3 * B_ * S_];
    u[i] = msk ? -__builtin_inff() : uv;
  }

  float mx = u[0];
#pragma unroll
  for (int i = 1; i < 8; ++i) mx = fmaxf(mx, u[i]);
#pragma unroll
  for (int off = 32; off; off >>= 1) mx = fmaxf(mx, __shfl_xor(mx, off));
  if (l == 0) red[w] = mx;
  __syncthreads();
  mx = fmaxf(fmaxf(red[0], red[1]), fmaxf(red[2], red[3]));
  __syncthreads();

  float p[8];
  float s = 0.f;
#pragma unroll
  for (int i = 0; i < 8; ++i) {
    p[i] = __builtin_amdgcn_exp2f((u[i] - mx) * 1.4426950408889634f);
    s += p[i];
  }
#pragma unroll
  for (int off = 32; off; off >>= 1) s += __shfl_xor(s, off);
  if (l == 0) red[w] = s;
  __syncthreads();
  s = red[0] + red[1] + red[2] + red[3];

  const float inv = 1.0f / s;
#pragma unroll
  for (int i = 0; i < 8; ++i) alpha[b * S_ + t + i * 256] = p[i] * inv;
}

// ---------------------------------------------------------------------------
// part[chunk][b][d] = sum over 128 s of alpha * ctx (fp32)
__global__ void k_wsum(const float* __restrict__ ctx, const float* __restrict__ alpha,
                       float* __restrict__ part) {
  __shared__ float red[3][512];
  const int b = blockIdx.x >> 4, chunk = blockIdx.x & 15;
  const int t = threadIdx.x;
  const int h0 = (t & 63) << 3;
  const int sw = t >> 6;
  const int s0 = chunk << 7;

  float acc[8] = {0.f, 0.f, 0.f, 0.f, 0.f, 0.f, 0.f, 0.f};
#pragma unroll 2
  for (int k = 0; k < 32; ++k) {
    const int s = s0 + sw + (k << 2);
    const float a = alpha[b * S_ + s];
    const f32x4* e = (const f32x4*)(ctx + ((size_t)(b * S_ + s)) * D_ + h0);
    f32x4 e0 = e[0], e1 = e[1];
#pragma unroll
    for (int j = 0; j < 4; ++j) acc[j] += a * e0[j];
#pragma unroll
    for (int j = 0; j < 4; ++j) acc[4 + j] += a * e1[j];
  }
  if (sw) {
#pragma unroll
    for (int j = 0; j < 8; ++j) red[sw - 1][h0 + j] = acc[j];
  }
  __syncthreads();
  if (sw == 0) {
#pragma unroll
    for (int j = 0; j < 8; ++j)
      part[((chunk << 6) + b) * 512 + h0 + j] =
          acc[j] + red[0][h0 + j] + red[1][h0 + j] + red[2][h0 + j];
  }
}

// ---------------------------------------------------------------------------
// k_tail: collapse part chunks into LDS wsum, then out1 = wsum.We^T + be
__global__ void k_tail(const float* __restrict__ part, const float* __restrict__ We,
                       const float* __restrict__ be, float* __restrict__ out1) {
  __shared__ float wsum_s[512];
  const int b = blockIdx.x, t = threadIdx.x;

  float s = 0.f;
#pragma unroll
  for (int c = 0; c < 16; ++c) s += part[((c << 6) + b) * 512 + t];
  wsum_s[t] = s;
  __syncthreads();

  const f32x4* wp = (const f32x4*)wsum_s;
  const f32x4* ep = (const f32x4*)(We + (size_t)t * D_);
  float acc = 0.f;
#pragma unroll 8
  for (int i = 0; i < D_ / 4; ++i) {
    f32x4 x = wp[i], y = ep[i];
    acc += x[0] * y[0] + x[1] * y[1] + x[2] * y[2] + x[3] * y[3];
  }
  out1[b * H_ + t] = acc + be[t];
}

// ---------------------------------------------------------------------------
extern "C" void kernel_launch(void* const* d_in, const int* in_sizes, int n_in,
                              void* d_out, int out_size, void* d_ws, size_t ws_size,
                              hipStream_t stream) {
  const float* hidden = (const float*)d_in[0];
  const float* ctx    = (const float*)d_in[1];
  const void*  mask   = d_in[2];
  const float* Wd     = (const float*)d_in[3];
  const float* bd     = (const float*)d_in[4];
  const float* We     = (const float*)d_in[5];
  const float* be     = (const float*)d_in[6];
  const float* V      = (const float*)d_in[7];

  float* out   = (float*)d_out;
  float* alpha = out;               // [B,S]
  float* out1  = out + B_ * S_;     // [B,H]

  // ws layout: ui4/part (2MB region) | di (128KB) | Web (512KB)
  char* ws = (char*)d_ws;
  const size_t off_u2  = 0;
  const size_t off_r3  = off_u2 + 4ull * B_ * S_ * 4;   // +2 MiB
  const size_t off_web = off_r3 + (size_t)B_ * H_ * 4;  // +128 KiB

  float* ui4  = (float*)(ws + off_u2);
  float* part = (float*)(ws + off_u2);
  float* di   = (float*)(ws + off_r3);
  unsigned short* Web = (unsigned short*)(ws + off_web);

  k_prep<<<256, 256, 0, stream>>>(hidden, Wd, bd, di, We, Web);
  k_ei_gemm<<<(B_ * S_ / 128) * 4, 256, 0, stream>>>(ctx, Web, be, V, di, ui4);
  k_softmax<<<B_, 256, 0, stream>>>(ui4, mask, alpha);
  k_wsum<<<B_ * 16, 256, 0, stream>>>(ctx, alpha, part);
  k_tail<<<B_, 512, 0, stream>>>(part, We, be, out1);
}

// Round 15
// 272.407 us; speedup vs baseline: 1.4247x; 1.4247x over previous
//
#include <hip/hip_runtime.h>
#include <cstdint>

// Problem constants (B,S,D,H) from the reference
#define B_ 64
#define S_ 2048
#define D_ 512
#define H_ 512

using f32x4  = __attribute__((ext_vector_type(4))) float;
using bf16x8 = __attribute__((ext_vector_type(8))) short;
using u32x2  = __attribute__((ext_vector_type(2))) unsigned int;

__device__ __forceinline__ unsigned short f2bf(float f) {
  unsigned u = __float_as_uint(f);
  u += 0x7FFFu + ((u >> 16) & 1u);   // round-to-nearest-even
  return (unsigned short)(u >> 16);
}
// packed f32x2 -> bf16x2 (RTE), hardware op (no builtin on gfx950)
__device__ __forceinline__ unsigned int cvtpk(float lo, float hi) {
  unsigned int r;
  asm("v_cvt_pk_bf16_f32 %0, %1, %2" : "=v"(r) : "v"(lo), "v"(hi));
  return r;
}
// tanh via v_exp_f32: 1 - 2/(exp2(2x*log2e)+1); exact saturation at +-inf
__device__ __forceinline__ float fast_tanh(float x) {
  float t = __builtin_amdgcn_exp2f(x * 2.8853900817779268f);
  return 1.0f - 2.0f * __builtin_amdgcn_rcpf(t + 1.0f);
}

// async global->LDS DMA, 16B/lane; dest = wave-uniform base + lane*16 (linear)
__device__ __forceinline__ void gl_lds16g(const void* g, void* l) {
  __builtin_amdgcn_global_load_lds(
      (const __attribute__((address_space(1))) unsigned int*)g,
      (__attribute__((address_space(3))) unsigned int*)l, 16, 0, 0);
}

__device__ __forceinline__ void barrier_raw() {
  asm volatile("" ::: "memory");
  __builtin_amdgcn_s_barrier();
  asm volatile("" ::: "memory");
}

// ---------------------------------------------------------------------------
// k_prep: blocks [0,128): di[b,h] = hidden[b,:].Wd[h,:] + bd[h]
//         blocks [128,256): We fp32 -> bf16 (32768 chunks of 8)
__global__ void k_prep(const float* __restrict__ hidden, const float* __restrict__ Wd,
                       const float* __restrict__ bd, float* __restrict__ di,
                       const float* __restrict__ We, unsigned short* __restrict__ Web) {
  if (blockIdx.x < 128) {
    int idx = blockIdx.x * 256 + threadIdx.x;   // 32768 total
    int h = idx >> 6;
    int b = idx & 63;
    const f32x4* hp = (const f32x4*)(hidden + (size_t)b * D_);
    const f32x4* wp = (const f32x4*)(Wd + (size_t)h * D_);
    float acc = 0.f;
#pragma unroll 8
    for (int i = 0; i < D_ / 4; ++i) {
      f32x4 x = hp[i], y = wp[i];
      acc += x[0] * y[0] + x[1] * y[1] + x[2] * y[2] + x[3] * y[3];
    }
    di[b * H_ + h] = acc + bd[h];
  } else {
    int i = (blockIdx.x - 128) * 256 + threadIdx.x;   // 32768 chunks
    const f32x4* p = (const f32x4*)(We + (size_t)i * 8);
    f32x4 a = p[0], b = p[1];
    bf16x8 o;
    o[0] = (short)f2bf(a[0]); o[1] = (short)f2bf(a[1]);
    o[2] = (short)f2bf(a[2]); o[3] = (short)f2bf(a[3]);
    o[4] = (short)f2bf(b[0]); o[5] = (short)f2bf(b[1]);
    o[6] = (short)f2bf(b[2]); o[7] = (short)f2bf(b[3]);
    *(bf16x8*)(Web + (size_t)i * 8) = o;
  }
}

// ---------------------------------------------------------------------------
// ei-GEMM: BM=64, BN=512 (FULL N per block -> A read from HBM exactly once,
// ui computed completely per block). 8 waves (1M x 8N), wave tile 64x64,
// acc[4][4] (64 AGPR). 512 thr, grid 2048.
// Staging per kstep (very light):
//   A: 64x32 fp32 = ONE f32x4 load + 2 cvt_pk + one ds_write_b64 per thread
//   B: 512x32 bf16 = 4 gl_lds DMAs per wave (Web, L2-resident)
// Pipeline (counted vmcnt; issue order A-load THEN B-DMA each iteration):
//   prologue: A0; B-DMA(buf0,k0); cvtA0->buf0 [vmcnt(4): B0 stays]; A1; B-DMA(buf1,k1)
//   iter kt:  vmcnt(5) [retires B(kt); A(kt+1)+B(kt+1) in flight]; lgkm(0); barrier
//             ds_read frags(buf[kt&1]); cvtA(kt+1)->buf[kt&1^1]; A-load(kt+2)
//             setprio(1) 16 MFMA setprio(0); barrier; B-DMA(buf[kt&1], kt+2)
// Unified XOR swizzle, both-sides: phys slot = logical ^ (row&3) ^ ((row>>2)&3);
// all fragment-base rows are multiples of 16 so the read offset collapses to
// the lane constant (lg ^ (lr&3) ^ ((lr>>2)&3))*8 for BOTH A and B. DMA dest
// linear, source pre-swizzled (both-sides-or-neither rule).
// launch_bounds(512,1): no register cap -> no cap-induced spill (R9/R13/R14 trap).
__global__ __launch_bounds__(512, 1) void k_ei_gemm(
    const float* __restrict__ A, const unsigned short* __restrict__ Bw,
    const float* __restrict__ be, const float* __restrict__ V,
    const float* __restrict__ di, float* __restrict__ ui) {
  __shared__ __align__(16) unsigned short ldsA[2][64 * 32];    // 4 KB each
  __shared__ __align__(16) unsigned short ldsB[2][512 * 32];   // 32 KB each
  __shared__ float ured[8][64];

  const int bid = blockIdx.x;          // 2048 blocks, 64 rows each
  const int row0 = bid << 6;

  const int t  = threadIdx.x;
  const int l  = t & 63;
  const int w  = t >> 6;               // 8 waves: 1M x 8N
  const int wn = w << 6;               // col base 0..448
  const int lr = l & 15;
  const int lg = l >> 4;

  // A: thread t -> row t>>3, fp32 col (t&7)*4 (8 lanes x 16B = full 128B row)
  const float* gA = A + (size_t)(row0 + (t >> 3)) * D_ + ((t & 7) << 2);
  // A ds_write_b64: row = t>>3, 8B granule g = t&7; logical 16B slot = g>>1;
  // phys = slot ^ (row&3) ^ ((row>>2)&3)
  const int eAslot = (((t >> 1) & 3) ^ ((t >> 3) & 3) ^ ((t >> 5) & 3));
  const int eA = (t >> 3) * 32 + eAslot * 8 + (t & 1) * 4;   // ushort units
  // B DMA: segment s = w*4 + d covers rows s*16..+15; lane l -> row s*16+(l>>2),
  // dest phys slot l&3 (linear); source logical = (l&3)^((l>>2)&3)^((l>>4)&3)
  const int segr = (l >> 2);           // row within segment
  const int srcg = ((l & 3) ^ ((l >> 2) & 3) ^ ((l >> 4) & 3));
  // fragment read slot offset (bf16 elems), same for A and B
  const int rs = ((lg ^ (lr & 3) ^ ((lr >> 2) & 3)) << 3);

  f32x4 areg;                           // single tiny A staging register

#define LOADA(kt) do { areg = *(const f32x4*)(gA + ((kt) << 5)); } while (0)
#define WRITEA(bf) do {                                             \
    u32x2 p_ = {cvtpk(areg[0], areg[1]), cvtpk(areg[2], areg[3])};  \
    *(u32x2*)&ldsA[bf][eA] = p_;                                    \
  } while (0)
#define DMAB(bf, kt) do {                                                      \
    _Pragma("unroll") for (int d_ = 0; d_ < 4; ++d_) {                         \
      const int s_ = w * 4 + d_;                                               \
      gl_lds16g(Bw + (size_t)(s_ * 16 + segr) * D_ + ((kt) << 5) + srcg * 8,   \
                &ldsB[bf][(s_ * 16) * 32]);                                    \
    }                                                                          \
  } while (0)

  f32x4 acc[4][4];
  const f32x4 z = {0.f, 0.f, 0.f, 0.f};
#pragma unroll
  for (int mi = 0; mi < 4; ++mi)
#pragma unroll
    for (int ni = 0; ni < 4; ++ni) acc[mi][ni] = z;

  // prologue
  LOADA(0);
  DMAB(0, 0);
  WRITEA(0);          // compiler inserts vmcnt(4): retires A0, B0 stays out
  LOADA(1);
  DMAB(1, 1);
  // outstanding now: [B0 x4, A1, B1 x4] = 9

  for (int kt = 0; kt < 16; ++kt) {
    if (kt < 15)
      asm volatile("s_waitcnt vmcnt(5) lgkmcnt(0)" ::: "memory");  // B(kt) done
    else
      asm volatile("s_waitcnt vmcnt(0) lgkmcnt(0)" ::: "memory");
    barrier_raw();                      // buf[kt&1] (A writes + B DMA) ready
    const int bf = kt & 1;

    bf16x8 af[4], bq[4];
#pragma unroll
    for (int mi = 0; mi < 4; ++mi)
      af[mi] = *(const bf16x8*)&ldsA[bf][(mi * 16 + lr) * 32 + rs];
#pragma unroll
    for (int ni = 0; ni < 4; ++ni)
      bq[ni] = *(const bf16x8*)&ldsB[bf][(wn + ni * 16 + lr) * 32 + rs];

    if (kt < 15) WRITEA(bf ^ 1);        // A(kt+1) -> other buf (readers done)
    if (kt < 14) LOADA(kt + 2);         // A(kt+2) in flight

    __builtin_amdgcn_s_setprio(1);
#pragma unroll
    for (int mi = 0; mi < 4; ++mi)
#pragma unroll
      for (int ni = 0; ni < 4; ++ni)
        acc[mi][ni] = __builtin_amdgcn_mfma_f32_16x16x32_bf16(
            af[mi], bq[ni], acc[mi][ni], 0, 0, 0);
    __builtin_amdgcn_s_setprio(0);

    barrier_raw();                      // all reads of buf[bf] retired
    if (kt < 14) DMAB(bf, kt + 2);      // B(kt+2) -> freed buf, flies onward
  }
#undef LOADA
#undef WRITEA
#undef DMAB

  // fused ui: this block covers ALL 512 columns -> complete ui rows.
  // C/D layout: col = lr, row = lg*4 + j within each 16x16 frag.
  const int b = row0 >> 11;   // 64 | 2048 -> block-uniform batch
  float uacc[4][4];
#pragma unroll
  for (int mi = 0; mi < 4; ++mi)
#pragma unroll
    for (int j = 0; j < 4; ++j) uacc[mi][j] = 0.f;

#pragma unroll
  for (int ni = 0; ni < 4; ++ni) {
    const int gc = wn + ni * 16 + lr;
    const float vv = V[gc];
    const float base = di[b * H_ + gc] + be[gc];
#pragma unroll
    for (int mi = 0; mi < 4; ++mi)
#pragma unroll
      for (int j = 0; j < 4; ++j)
        uacc[mi][j] += vv * fast_tanh(base + acc[mi][ni][j]);
  }
  // reduce across the 16 lr-lanes; lanes lr==0 (lg=0..3) hold 4-row sums
#pragma unroll
  for (int mi = 0; mi < 4; ++mi)
#pragma unroll
    for (int j = 0; j < 4; ++j) {
      float s = uacc[mi][j];
      s += __shfl_xor(s, 1);
      s += __shfl_xor(s, 2);
      s += __shfl_xor(s, 4);
      s += __shfl_xor(s, 8);
      if (lr == 0) ured[w][mi * 16 + (lg << 2) + j] = s;
    }
  __syncthreads();
  if (t < 64) {
    float s = 0.f;
#pragma unroll
    for (int ww = 0; ww < 8; ++ww) s += ured[ww][t];
    ui[row0 + t] = s;
  }
}

// ---------------------------------------------------------------------------
// softmax over S per batch row, applying mask -> -inf.
// Mask dtype (bool-bytes vs int32) detected per block from word high-bytes
// (scan limited to first 128KB so it is in-bounds under both layouts).
__global__ void k_softmax(const float* __restrict__ ui, const void* __restrict__ mask,
                          float* __restrict__ alpha) {
  __shared__ float red[4];
  __shared__ int sfl;
  const int b = blockIdx.x, t = threadIdx.x;
  const int l = t & 63, w = t >> 6;

  if (t == 0) sfl = 0;
  const unsigned int* mw = (const unsigned int*)mask;
  unsigned det = (mw[b * 512 + t] | mw[b * 512 + 256 + t]) & 0xFFFFFF00u;
  __syncthreads();
  if (det) atomicOr(&sfl, 1);
  __syncthreads();
  const int fl = sfl;   // 1 => byte layout

  float u[8];
#pragma unroll
  for (int i = 0; i < 8; ++i) {
    const int idx = b * S_ + t + i * 256;
    const int msk = fl ? (int)((const unsigned char*)mask)[idx]
                       : ((const int*)mask)[idx];
    u[i] = msk ? -__builtin_inff() : ui[idx];
  }

  float mx = u[0];
#pragma unroll
  for (int i = 1; i < 8; ++i) mx = fmaxf(mx, u[i]);
#pragma unroll
  for (int off = 32; off; off >>= 1) mx = fmaxf(mx, __shfl_xor(mx, off));
  if (l == 0) red[w] = mx;
  __syncthreads();
  mx = fmaxf(fmaxf(red[0], red[1]), fmaxf(red[2], red[3]));
  __syncthreads();

  float p[8];
  float s = 0.f;
#pragma unroll
  for (int i = 0; i < 8; ++i) {
    p[i] = __builtin_amdgcn_exp2f((u[i] - mx) * 1.4426950408889634f);
    s += p[i];
  }
#pragma unroll
  for (int off = 32; off; off >>= 1) s += __shfl_xor(s, off);
  if (l == 0) red[w] = s;
  __syncthreads();
  s = red[0] + red[1] + red[2] + red[3];

  const float inv = 1.0f / s;
#pragma unroll
  for (int i = 0; i < 8; ++i) alpha[b * S_ + t + i * 256] = p[i] * inv;
}

// ---------------------------------------------------------------------------
// part[chunk][b][d] = sum over 128 s of alpha * ctx (fp32)
__global__ void k_wsum(const float* __restrict__ ctx, const float* __restrict__ alpha,
                       float* __restrict__ part) {
  __shared__ float red[3][512];
  const int b = blockIdx.x >> 4, chunk = blockIdx.x & 15;
  const int t = threadIdx.x;
  const int h0 = (t & 63) << 3;
  const int sw = t >> 6;
  const int s0 = chunk << 7;

  float acc[8] = {0.f, 0.f, 0.f, 0.f, 0.f, 0.f, 0.f, 0.f};
#pragma unroll 2
  for (int k = 0; k < 32; ++k) {
    const int s = s0 + sw + (k << 2);
    const float a = alpha[b * S_ + s];
    const f32x4* e = (const f32x4*)(ctx + ((size_t)(b * S_ + s)) * D_ + h0);
    f32x4 e0 = e[0], e1 = e[1];
#pragma unroll
    for (int j = 0; j < 4; ++j) acc[j] += a * e0[j];
#pragma unroll
    for (int j = 0; j < 4; ++j) acc[4 + j] += a * e1[j];
  }
  if (sw) {
#pragma unroll
    for (int j = 0; j < 8; ++j) red[sw - 1][h0 + j] = acc[j];
  }
  __syncthreads();
  if (sw == 0) {
#pragma unroll
    for (int j = 0; j < 8; ++j)
      part[((chunk << 6) + b) * 512 + h0 + j] =
          acc[j] + red[0][h0 + j] + red[1][h0 + j] + red[2][h0 + j];
  }
}

// ---------------------------------------------------------------------------
// k_tail: collapse part chunks into LDS wsum, then out1 = wsum.We^T + be
__global__ void k_tail(const float* __restrict__ part, const float* __restrict__ We,
                       const float* __restrict__ be, float* __restrict__ out1) {
  __shared__ float wsum_s[512];
  const int b = blockIdx.x, t = threadIdx.x;

  float s = 0.f;
#pragma unroll
  for (int c = 0; c < 16; ++c) s += part[((c << 6) + b) * 512 + t];
  wsum_s[t] = s;
  __syncthreads();

  const f32x4* wp = (const f32x4*)wsum_s;
  const f32x4* ep = (const f32x4*)(We + (size_t)t * D_);
  float acc = 0.f;
#pragma unroll 8
  for (int i = 0; i < D_ / 4; ++i) {
    f32x4 x = wp[i], y = ep[i];
    acc += x[0] * y[0] + x[1] * y[1] + x[2] * y[2] + x[3] * y[3];
  }
  out1[b * H_ + t] = acc + be[t];
}

// ---------------------------------------------------------------------------
extern "C" void kernel_launch(void* const* d_in, const int* in_sizes, int n_in,
                              void* d_out, int out_size, void* d_ws, size_t ws_size,
                              hipStream_t stream) {
  const float* hidden = (const float*)d_in[0];
  const float* ctx    = (const float*)d_in[1];
  const void*  mask   = d_in[2];
  const float* Wd     = (const float*)d_in[3];
  const float* bd     = (const float*)d_in[4];
  const float* We     = (const float*)d_in[5];
  const float* be     = (const float*)d_in[6];
  const float* V      = (const float*)d_in[7];

  float* out   = (float*)d_out;
  float* alpha = out;               // [B,S]
  float* out1  = out + B_ * S_;     // [B,H]

  // ws layout: ui (512KB) | part (2MB) | di (128KB) | Web (512KB)
  char* ws = (char*)d_ws;
  const size_t off_ui   = 0;
  const size_t off_part = off_ui + (size_t)B_ * S_ * 4;       // +512 KiB
  const size_t off_di   = off_part + 16ull * B_ * D_ * 4;     // +2 MiB
  const size_t off_web  = off_di + (size_t)B_ * H_ * 4;       // +128 KiB

  float* ui   = (float*)(ws + off_ui);
  float* part = (float*)(ws + off_part);
  float* di   = (float*)(ws + off_di);
  unsigned short* Web = (unsigned short*)(ws + off_web);

  k_prep<<<256, 256, 0, stream>>>(hidden, Wd, bd, di, We, Web);
  k_ei_gemm<<<B_ * S_ / 64, 512, 0, stream>>>(ctx, Web, be, V, di, ui);
  k_softmax<<<B_, 256, 0, stream>>>(ui, mask, alpha);
  k_wsum<<<B_ * 16, 256, 0, stream>>>(ctx, alpha, part);
  k_tail<<<B_, 512, 0, stream>>>(part, We, be, out1);
}